// Round 1
// 152.312 us; speedup vs baseline: 1.0834x; 1.0834x over previous
//
#include <hip/hip_runtime.h>
#include <math.h>

#define Bb 2
#define Ll 2048
#define Dm 1024
#define Ns 16
#define Rr 64
#define Ee 96          // DT_RANK + 2*D_STATE
#define XPS 8          // K-splits for xproj GEMM (K-slice = 128)
#define BLK (Bb*Ll)    // 4096 rows
#define NTHR 256
#define LOG2E 1.4426950408889634f
#define LN2   0.6931471805599453f

__device__ inline float ex2(float x) {
#if __has_builtin(__builtin_amdgcn_exp2f)
    return __builtin_amdgcn_exp2f(x);
#else
    return exp2f(x);
#endif
}
__device__ inline float lg2(float x) {
#if __has_builtin(__builtin_amdgcn_logf)
    return __builtin_amdgcn_logf(x);
#else
    return log2f(x);
#endif
}
__device__ inline float softplus_f(float z) {
    // softplus = max(z,0) + ln(1 + exp(-|z|)); v_exp/v_log are base-2
    float e = ex2(-fabsf(z) * LOG2E);
    return fmaxf(z, 0.f) + lg2(1.f + e) * LN2;
}

// ========== Kernel 1: xp_part[ks][bl][e] = sum_{k in slice} x[bl][k]*xw[e][k] ==========
// 64 mtiles (BM=64) x 8 ksplits = 512 blocks. K-slice 128, staged in 4 sub-chunks of 32.
// LDS is k-major so fragment loads are ds_read_b128 / b64 (was 10x ds_read_b32 per k).
__global__ void __launch_bounds__(NTHR)
k_xproj(const float* __restrict__ x, const float* __restrict__ xw,
        float* __restrict__ xp_part) {
    __shared__ __align__(16) float xs[32 * 68];    // [k][row], stride 68 (16B-mult)
    __shared__ __align__(16) float wsh[32 * 100];  // [k][e],   stride 100 (16B-mult)
    int bx = blockIdx.x;
    int ks = bx & 7, mt = bx >> 3;
    int i0 = mt * 64;
    int tid = threadIdx.x;
    int tx = tid & 15, ty = tid >> 4;      // tile 4(i) x 6(j)
    float acc[4][6];
#pragma unroll
    for (int ii = 0; ii < 4; ++ii)
#pragma unroll
        for (int jj = 0; jj < 6; ++jj) acc[ii][jj] = 0.f;

    for (int kc = 0; kc < 4; ++kc) {
        int k0 = ks * 128 + kc * 32;
        for (int t = tid; t < 512; t += NTHR) {          // x: 64 rows x 32 k
            int r = t >> 3, c = (t & 7) * 4;
            float4 v = *(const float4*)(x + (size_t)(i0 + r) * Dm + k0 + c);
            xs[(c+0)*68+r] = v.x; xs[(c+1)*68+r] = v.y;
            xs[(c+2)*68+r] = v.z; xs[(c+3)*68+r] = v.w;
        }
        for (int t = tid; t < 768; t += NTHR) {          // w: 96 rows x 32 k
            int r = t >> 3, c = (t & 7) * 4;
            float4 v = *(const float4*)(xw + (size_t)r * Dm + k0 + c);
            wsh[(c+0)*100+r] = v.x; wsh[(c+1)*100+r] = v.y;
            wsh[(c+2)*100+r] = v.z; wsh[(c+3)*100+r] = v.w;
        }
        __syncthreads();
#pragma unroll 8
        for (int k = 0; k < 32; ++k) {
            float4 xv = *(const float4*)(xs + k*68 + ty*4);
            float2 w0 = *(const float2*)(wsh + k*100 + tx*6 + 0);
            float2 w1 = *(const float2*)(wsh + k*100 + tx*6 + 2);
            float2 w2 = *(const float2*)(wsh + k*100 + tx*6 + 4);
            float xr[4] = {xv.x, xv.y, xv.z, xv.w};
            float wr[6] = {w0.x, w0.y, w1.x, w1.y, w2.x, w2.y};
#pragma unroll
            for (int ii = 0; ii < 4; ++ii)
#pragma unroll
                for (int jj = 0; jj < 6; ++jj)
                    acc[ii][jj] = fmaf(xr[ii], wr[jj], acc[ii][jj]);
        }
        __syncthreads();
    }
#pragma unroll
    for (int ii = 0; ii < 4; ++ii)
#pragma unroll
        for (int jj = 0; jj < 6; ++jj)
            xp_part[((size_t)ks * BLK + (i0 + ty*4 + ii)) * Ee + tx*6 + jj] = acc[ii][jj];
}

// ========== Kernel 2: reduce K-splits -> xp (float4 grid-exact) ==========
__global__ void __launch_bounds__(NTHR)
k_prep(const float* __restrict__ xp_part, float* __restrict__ xp) {
    int g = blockIdx.x * NTHR + threadIdx.x;    // 98304 float4s
    const float4* p = (const float4*)xp_part;
    float4 s = p[g];
#pragma unroll
    for (int i = 1; i < XPS; ++i) {
        float4 v = p[(size_t)i * (BLK * Ee / 4) + g];
        s.x += v.x; s.y += v.y; s.z += v.z; s.w += v.w;
    }
    ((float4*)xp)[g] = s;
}

// ========== Kernel 3: delta[bl][d] = softplus(xp[bl][:64] . dtw[d] + dtb[d]) ==========
// M=4096 N=1024 K=64. BM=128, BN=64 -> 32x16 = 512 blocks. Thread tile 8x4.
// k-major LDS: fragment loads are 3x ds_read_b128 per k (was 8x b32).
__global__ void __launch_bounds__(NTHR)
k_delta(const float* __restrict__ xp, const float* __restrict__ dtw,
        const float* __restrict__ dtb, float* __restrict__ delta) {
    __shared__ __align__(16) float xs[64 * 136];   // [k][row], stride 136
    __shared__ __align__(16) float wsh[64 * 68];   // [k][d],   stride 68
    int bx = blockIdx.x;
    int nt = bx & 15, mt = bx >> 4;
    int i0 = mt * 128, j0 = nt * 64;
    int tid = threadIdx.x, tx = tid & 15, ty = tid >> 4;

    for (int t = tid; t < 2048; t += NTHR) {       // xp: 128 rows x 64 k
        int r = t >> 4, c = (t & 15) * 4;
        float4 v = *(const float4*)(xp + (size_t)(i0 + r) * Ee + c);
        xs[(c+0)*136+r] = v.x; xs[(c+1)*136+r] = v.y;
        xs[(c+2)*136+r] = v.z; xs[(c+3)*136+r] = v.w;
    }
    for (int t = tid; t < 1024; t += NTHR) {       // dtw: 64 d x 64 k
        int r = t >> 4, c = (t & 15) * 4;
        float4 w = *(const float4*)(dtw + (size_t)(j0 + r) * Rr + c);
        wsh[(c+0)*68+r] = w.x; wsh[(c+1)*68+r] = w.y;
        wsh[(c+2)*68+r] = w.z; wsh[(c+3)*68+r] = w.w;
    }
    __syncthreads();

    float acc[8][4];
#pragma unroll
    for (int ii = 0; ii < 8; ++ii)
#pragma unroll
        for (int jj = 0; jj < 4; ++jj) acc[ii][jj] = 0.f;
#pragma unroll 8
    for (int k = 0; k < 64; ++k) {
        float4 xa = *(const float4*)(xs + k*136 + ty*8 + 0);
        float4 xb = *(const float4*)(xs + k*136 + ty*8 + 4);
        float4 wv = *(const float4*)(wsh + k*68 + tx*4);
        float xr[8] = {xa.x,xa.y,xa.z,xa.w, xb.x,xb.y,xb.z,xb.w};
        float wr[4] = {wv.x, wv.y, wv.z, wv.w};
#pragma unroll
        for (int ii = 0; ii < 8; ++ii)
#pragma unroll
            for (int jj = 0; jj < 4; ++jj)
                acc[ii][jj] = fmaf(xr[ii], wr[jj], acc[ii][jj]);
    }
    int d0 = j0 + tx * 4;
    float4 bias = *(const float4*)(dtb + d0);
#pragma unroll
    for (int ii = 0; ii < 8; ++ii) {
        int bl = i0 + ty*8 + ii;
        float4 o;
        o.x = softplus_f(acc[ii][0] + bias.x);
        o.y = softplus_f(acc[ii][1] + bias.y);
        o.z = softplus_f(acc[ii][2] + bias.z);
        o.w = softplus_f(acc[ii][3] + bias.w);
        *(float4*)(delta + (size_t)bl * Dm + d0) = o;
    }
}

// ---- helper: load A row, pre-scaled by log2(e), into regs ----
__device__ inline void load_a2(const float* __restrict__ A_log, int d, float* a2) {
    const float4* Ap = (const float4*)(A_log + (size_t)d * Ns);
    float4 a0 = Ap[0], a1 = Ap[1], a2v = Ap[2], a3 = Ap[3];
    float tmp[Ns] = {a0.x,a0.y,a0.z,a0.w, a1.x,a1.y,a1.z,a1.w,
                     a2v.x,a2v.y,a2v.z,a2v.w, a3.x,a3.y,a3.z,a3.w};
#pragma unroll
    for (int n = 0; n < Ns; ++n) a2[n] = -__expf(tmp[n]) * LOG2E;
}

// ========== Kernel 4: per-chunk local scan (h0=0) -> Ec, Sc.  NO LDS. ==========
template<int CHv>
__global__ void __launch_bounds__(NTHR)
k_scan_part(const float* __restrict__ delta, const float* __restrict__ x,
            const float* __restrict__ xp, const float* __restrict__ A_log,
            float* __restrict__ Ec, float* __restrict__ Sc) {
    constexpr int CLv = Ll / CHv;
    int bx = blockIdx.x;
    int dblk = bx & 3, chunk = (bx >> 2) & (CHv - 1), b = bx >> 2 >> __builtin_ctz(CHv);
    int tid = threadIdx.x;
    int d = dblk * 256 + tid;
    int row0 = b * Ll + chunk * CLv;

    float a2[Ns], h[Ns];
    load_a2(A_log, d, a2);
#pragma unroll
    for (int n = 0; n < Ns; ++n) h[n] = 0.f;
    float sd = 0.f;

#pragma unroll 4
    for (int t = 0; t < CLv; ++t) {
        size_t row = (size_t)(row0 + t);
        float dl = delta[row * Dm + d];
        float xv = x[row * Dm + d];
        const float* bp = xp + row * Ee + Rr;
        float4 B0 = *(const float4*)(bp + 0),  B1 = *(const float4*)(bp + 4);
        float4 B2 = *(const float4*)(bp + 8),  B3 = *(const float4*)(bp + 12);
        float Bv[Ns] = {B0.x,B0.y,B0.z,B0.w, B1.x,B1.y,B1.z,B1.w,
                        B2.x,B2.y,B2.z,B2.w, B3.x,B3.y,B3.z,B3.w};
        float dx = dl * xv;
        sd += dl;
#pragma unroll
        for (int n = 0; n < Ns; ++n)
            h[n] = fmaf(ex2(dl * a2[n]), h[n], dx * Bv[n]);
    }
    size_t base = ((size_t)b * CHv + chunk) * Dm + d;
    float4* Ep = (float4*)(Ec + base * Ns);
    Ep[0] = make_float4(h[0],  h[1],  h[2],  h[3]);
    Ep[1] = make_float4(h[4],  h[5],  h[6],  h[7]);
    Ep[2] = make_float4(h[8],  h[9],  h[10], h[11]);
    Ep[3] = make_float4(h[12], h[13], h[14], h[15]);
    Sc[base] = sd;
}

// ========== Kernel 5a: within-group (CPG chunks) combine. 16 waves/CU, CPG iters. ==========
// Writes group-local chunk prefixes (Hloc, Spre) and group aggregates (Eg, Sg).
template<int CHv, int G>
__global__ void __launch_bounds__(NTHR)
k_comb1(const float* __restrict__ Ec, const float* __restrict__ Sc,
        const float* __restrict__ A_log, float* __restrict__ Hloc,
        float* __restrict__ Spre, float* __restrict__ Eg, float* __restrict__ Sg) {
    constexpr int CPG = CHv / G;
    int gid = blockIdx.x * NTHR + threadIdx.x;   // Bb*G*Dm*Ns = 262144
    int n = gid & (Ns - 1);
    int d = (gid >> 4) & (Dm - 1);
    int g = (gid >> 14) & (G - 1);
    int b = gid >> 17;
    float a2 = -__expf(A_log[d * Ns + n]) * LOG2E;
    float h = 0.f, S = 0.f;
#pragma unroll
    for (int j = 0; j < CPG; ++j) {
        size_t base = ((size_t)b * CHv + g * CPG + j) * Dm + d;
        float e  = Ec[base * Ns + n];
        float sc = Sc[base];
        Hloc[base * Ns + n] = h;
        if (n == 0) Spre[base] = S;
        h = fmaf(ex2(a2 * sc), h, e);
        S += sc;
    }
    size_t gb = ((size_t)b * G + g) * Dm + d;
    Eg[gb * Ns + n] = h;
    if (n == 0) Sg[gb] = S;
}

// ========== Kernel 5b: across-group combine (G iters, tiny). ==========
template<int G>
__global__ void __launch_bounds__(NTHR)
k_comb2(const float* __restrict__ Eg, const float* __restrict__ Sg,
        const float* __restrict__ A_log, float* __restrict__ Hg) {
    int gid = blockIdx.x * NTHR + threadIdx.x;   // Bb*Dm*Ns = 32768
    int n = gid & (Ns - 1);
    int d = (gid >> 4) & (Dm - 1);
    int b = gid >> 14;
    float a2 = -__expf(A_log[d * Ns + n]) * LOG2E;
    float h = 0.f;
#pragma unroll
    for (int g = 0; g < G; ++g) {
        size_t gb = ((size_t)b * G + g) * Dm + d;
        Hg[gb * Ns + n] = h;
        h = fmaf(ex2(a2 * Sg[gb]), h, Eg[gb * Ns + n]);
    }
}

// ========== Kernel 6: full scan; h_in recombined in prologue from Hloc/Spre/Hg. ==========
template<int CHv, int G>
__global__ void __launch_bounds__(NTHR)
k_scan_full(const float* __restrict__ delta, const float* __restrict__ x,
            const float* __restrict__ xp, const float* __restrict__ A_log,
            const float* __restrict__ Dp, const float* __restrict__ Hloc,
            const float* __restrict__ Spre, const float* __restrict__ Hg,
            float* __restrict__ out) {
    constexpr int CLv = Ll / CHv;
    constexpr int CPG = CHv / G;
    int bx = blockIdx.x;
    int dblk = bx & 3, chunk = (bx >> 2) & (CHv - 1), b = bx >> 2 >> __builtin_ctz(CHv);
    int tid = threadIdx.x;
    int d = dblk * 256 + tid;
    int row0 = b * Ll + chunk * CLv;

    float a2[Ns], h[Ns];
    load_a2(A_log, d, a2);
    size_t base = ((size_t)b * CHv + chunk) * Dm + d;
    size_t gb   = ((size_t)b * G + chunk / CPG) * Dm + d;
    {
        float sp = Spre[base];
        const float4* Hl = (const float4*)(Hloc + base * Ns);
        const float4* Hp = (const float4*)(Hg + gb * Ns);
        float4 l0 = Hl[0], l1 = Hl[1], l2 = Hl[2], l3 = Hl[3];
        float4 g0 = Hp[0], g1 = Hp[1], g2 = Hp[2], g3 = Hp[3];
        float lv[Ns] = {l0.x,l0.y,l0.z,l0.w, l1.x,l1.y,l1.z,l1.w,
                        l2.x,l2.y,l2.z,l2.w, l3.x,l3.y,l3.z,l3.w};
        float gv[Ns] = {g0.x,g0.y,g0.z,g0.w, g1.x,g1.y,g1.z,g1.w,
                        g2.x,g2.y,g2.z,g2.w, g3.x,g3.y,g3.z,g3.w};
#pragma unroll
        for (int n = 0; n < Ns; ++n) h[n] = fmaf(ex2(a2[n] * sp), gv[n], lv[n]);
    }
    float Dval = Dp[d];

#pragma unroll 4
    for (int t = 0; t < CLv; ++t) {
        size_t row = (size_t)(row0 + t);
        float dl = delta[row * Dm + d];
        float xv = x[row * Dm + d];
        const float* bp = xp + row * Ee + Rr;
        float4 B0 = *(const float4*)(bp + 0),  B1 = *(const float4*)(bp + 4);
        float4 B2 = *(const float4*)(bp + 8),  B3 = *(const float4*)(bp + 12);
        float4 C0 = *(const float4*)(bp + 16), C1 = *(const float4*)(bp + 20);
        float4 C2 = *(const float4*)(bp + 24), C3 = *(const float4*)(bp + 28);
        float Bv[Ns] = {B0.x,B0.y,B0.z,B0.w, B1.x,B1.y,B1.z,B1.w,
                        B2.x,B2.y,B2.z,B2.w, B3.x,B3.y,B3.z,B3.w};
        float Cv[Ns] = {C0.x,C0.y,C0.z,C0.w, C1.x,C1.y,C1.z,C1.w,
                        C2.x,C2.y,C2.z,C2.w, C3.x,C3.y,C3.z,C3.w};
        float dx = dl * xv;
        float ya[4] = {0.f, 0.f, 0.f, 0.f};
#pragma unroll
        for (int n = 0; n < Ns; ++n) {
            h[n] = fmaf(ex2(dl * a2[n]), h[n], dx * Bv[n]);
            ya[n & 3] = fmaf(h[n], Cv[n], ya[n & 3]);
        }
        out[row * Dm + d] = fmaf(xv, Dval, (ya[0] + ya[1]) + (ya[2] + ya[3]));
    }
}

extern "C" void kernel_launch(void* const* d_in, const int* in_sizes, int n_in,
                              void* d_out, int out_size, void* d_ws, size_t ws_size,
                              hipStream_t stream) {
    const float* x     = (const float*)d_in[0];
    const float* A_log = (const float*)d_in[1];
    const float* Dp    = (const float*)d_in[2];
    const float* xw    = (const float*)d_in[3];
    const float* dtw   = (const float*)d_in[4];
    const float* dtb   = (const float*)d_in[5];
    float* out = (float*)d_out;
    float* ws  = (float*)d_ws;

    // layout (floats):
    //   xp      : 393216
    //   delta   : 4194304
    //   S3 region (aliased):
    //     phase 1 : xp_part = 8 * 393216 = 3145728   [dead after k_prep]
    //     phase 4+: Ec | Sc | Hloc | Spre | Eg | Sg | Hg
    float* xp      = ws;
    float* delta   = xp + 393216;
    float* S3      = delta + 4194304;
    float* xp_part = S3;

    k_xproj<<<dim3(512), dim3(NTHR), 0, stream>>>(x, xw, xp_part);
    k_prep <<<dim3(384), dim3(NTHR), 0, stream>>>(xp_part, xp);
    k_delta<<<dim3(512), dim3(NTHR), 0, stream>>>(xp, dtw, dtb, delta);

    constexpr int G = 8;
    // CH=128: S3 = Ec 4194304 + Sc 262144 + Hloc 4194304 + Spre 262144
    //            + Eg 262144 + Sg 16384 + Hg 262144 = 9453568 floats
    size_t s3_128 = (size_t)Bb*128*Dm*Ns + (size_t)Bb*128*Dm + (size_t)Bb*128*Dm*Ns
                  + (size_t)Bb*128*Dm + (size_t)Bb*G*Dm*Ns + (size_t)Bb*G*Dm
                  + (size_t)Bb*G*Dm*Ns;
    size_t need128 = ((size_t)393216 + 4194304 + s3_128) * 4;
    if (ws_size >= need128) {
        constexpr int CHv = 128;
        float* Ec   = S3;
        float* Sc   = Ec   + (size_t)Bb*CHv*Dm*Ns;
        float* Hloc = Sc   + (size_t)Bb*CHv*Dm;
        float* Spre = Hloc + (size_t)Bb*CHv*Dm*Ns;
        float* Eg   = Spre + (size_t)Bb*CHv*Dm;
        float* Sg   = Eg   + (size_t)Bb*G*Dm*Ns;
        float* Hg   = Sg   + (size_t)Bb*G*Dm;
        k_scan_part<CHv>  <<<dim3(Bb*CHv*4), dim3(NTHR), 0, stream>>>(delta, x, xp, A_log, Ec, Sc);
        k_comb1<CHv, G>   <<<dim3(Bb*G*Dm*Ns/NTHR), dim3(NTHR), 0, stream>>>(Ec, Sc, A_log, Hloc, Spre, Eg, Sg);
        k_comb2<G>        <<<dim3(Bb*Dm*Ns/NTHR), dim3(NTHR), 0, stream>>>(Eg, Sg, A_log, Hg);
        k_scan_full<CHv,G><<<dim3(Bb*CHv*4), dim3(NTHR), 0, stream>>>(delta, x, xp, A_log, Dp, Hloc, Spre, Hg, out);
    } else {
        constexpr int CHv = 64;
        float* Ec   = S3;
        float* Sc   = Ec   + (size_t)Bb*CHv*Dm*Ns;
        float* Hloc = Sc   + (size_t)Bb*CHv*Dm;
        float* Spre = Hloc + (size_t)Bb*CHv*Dm*Ns;
        float* Eg   = Spre + (size_t)Bb*CHv*Dm;
        float* Sg   = Eg   + (size_t)Bb*G*Dm*Ns;
        float* Hg   = Sg   + (size_t)Bb*G*Dm;
        k_scan_part<CHv>  <<<dim3(Bb*CHv*4), dim3(NTHR), 0, stream>>>(delta, x, xp, A_log, Ec, Sc);
        k_comb1<CHv, G>   <<<dim3(Bb*G*Dm*Ns/NTHR), dim3(NTHR), 0, stream>>>(Ec, Sc, A_log, Hloc, Spre, Eg, Sg);
        k_comb2<G>        <<<dim3(Bb*Dm*Ns/NTHR), dim3(NTHR), 0, stream>>>(Eg, Sg, A_log, Hg);
        k_scan_full<CHv,G><<<dim3(Bb*CHv*4), dim3(NTHR), 0, stream>>>(delta, x, xp, A_log, Dp, Hloc, Spre, Hg, out);
    }
}